// Round 1
// 645.838 us; speedup vs baseline: 1.0088x; 1.0088x over previous
//
#include <hip/hip_runtime.h>
#include <math.h>

#define BB 128
#define SS 2048
#define HH 512
#define LL 11

typedef float vf4 __attribute__((ext_vector_type(4)));

// Blocks [0, COPYBLK): independent contri copy for b >= 10 (overlaps streaming).
// Blocks [COPYBLK, ...): masked row max + argmax, length-aware early exit.
#define COPYBLK 944  // (BB-10)*SS/256 exactly

__global__ __launch_bounds__(256) void rowmax_kernel(
    const float* __restrict__ x,
    const int* __restrict__ lengths,
    const float* __restrict__ contri,
    float* __restrict__ pool,
    int* __restrict__ idx_out,
    float* __restrict__ out2) {
  if (blockIdx.x < COPYBLK) {
    // ---- plain copy rows for b >= 10 (no dependence on rowmax) ----
    int i = blockIdx.x * 256 + threadIdx.x;
    int t = 10 * SS + i;          // i < (BB-10)*SS exactly, no bounds check
    out2[t * 3 + 0] = contri[t * 2 + 0];
    out2[t * 3 + 1] = contri[t * 2 + 1];
    out2[t * 3 + 2] = 0.f;
    return;
  }

  int wave = (blockIdx.x - COPYBLK) * 4 + (threadIdx.x >> 6);  // row in [0, B*H)
  int lane = threadIdx.x & 63;
  int b = wave >> 9;              // H == 512
  int len = lengths[b];           // len >= 1 guaranteed
  const vf4* row = (const vf4*)(x + (size_t)wave * SS);

  // Only fetch chunks that contain valid elements: nj = ceil(len/256)
  int nj = (len + 255) >> 8;

  float best = -INFINITY;
  int bidx = 0;
  vf4 v = row[lane];              // chunk 0 always needed (len >= 1)
  for (int j = 0; j < nj; ++j) {
    vf4 nxt = v;
    if (j + 1 < nj)               // wave-uniform; prefetch next chunk
      nxt = row[(j + 1) * 64 + lane];
    int si = (j * 64 + lane) * 4;
    float a;
    a = (si + 0 < len) ? v.x : -INFINITY;
    if (a > best) { best = a; bidx = si + 0; }
    a = (si + 1 < len) ? v.y : -INFINITY;
    if (a > best) { best = a; bidx = si + 1; }
    a = (si + 2 < len) ? v.z : -INFINITY;
    if (a > best) { best = a; bidx = si + 2; }
    a = (si + 3 < len) ? v.w : -INFINITY;
    if (a > best) { best = a; bidx = si + 3; }
    v = nxt;
  }

  // cross-lane reduce, first-occurrence tie-break (min index on equal value)
#pragma unroll
  for (int off = 32; off > 0; off >>= 1) {
    float ov = __shfl_down(best, off);
    int oi = __shfl_down(bidx, off);
    if (ov > best || (ov == best && oi < bidx)) { best = ov; bidx = oi; }
  }
  if (lane == 0) {
    pool[wave] = best;
    idx_out[wave] = bidx;
  }
}

// ---------------------------------------------------------------------------
// Kernel 2: fused epilogue.
//   blocks [0,10):   per-batch denom + total + LDS scatter + output row
//   blocks [10,138): attn = pool @ fc_w.T for b = blockIdx-10
// ---------------------------------------------------------------------------
__global__ __launch_bounds__(256) void epilogue_kernel(
    const float* __restrict__ pool,
    const int* __restrict__ idx_in,
    const float* __restrict__ fcw,
    const float* __restrict__ contri,
    float* __restrict__ attn_out,
    float* __restrict__ out2) {
  int tid = threadIdx.x;
  int wv = tid >> 6;
  int lane = tid & 63;

  if (blockIdx.x < 10) {
    // ---- special batch: contributions + LDS scatter + row write ----
    int b = blockIdx.x;
    __shared__ float sp[HH];     // pool row
    __shared__ float sden[LL];   // 100/denom
    __shared__ float sch[SS];    // scatter target (ch2 row)

    for (int h = tid; h < HH; h += 256) sp[h] = pool[b * HH + h];
    for (int s = tid; s < SS; s += 256) sch[s] = 0.f;
    __syncthreads();

    // denom[l] = sum_h relu(p*w) + H*1e-4 ; store reciprocal*100
    for (int l = wv; l < LL; l += 4) {
      float s = 0.f;
#pragma unroll
      for (int k = 0; k < HH / 64; ++k) {
        int h = k * 64 + lane;
        s += fmaxf(sp[h] * fcw[l * HH + h], 0.f);
      }
#pragma unroll
      for (int off = 32; off > 0; off >>= 1) s += __shfl_down(s, off);
      if (lane == 0) sden[l] = 100.f / (s + (float)HH * 1e-4f);
    }
    __syncthreads();

    // total[hh] and scatter into LDS
    for (int hh = tid; hh < HH; hh += 256) {
      float p = sp[hh];
      float tot = 0.f;
#pragma unroll
      for (int l = 0; l < LL; ++l)
        tot += (fmaxf(p * fcw[l * HH + hh], 0.f) + 1e-4f) * sden[l];
      atomicAdd(&sch[idx_in[b * HH + hh]], tot);
    }
    __syncthreads();

    // write output rows: (contri0, contri1, ch2)
    for (int s = tid; s < SS; s += 256) {
      int t = b * SS + s;
      out2[t * 3 + 0] = contri[t * 2 + 0];
      out2[t * 3 + 1] = contri[t * 2 + 1];
      out2[t * 3 + 2] = sch[s];
    }
  } else {
    // ---- attn for one batch ----
    int b = blockIdx.x - 10;
    const float* p = pool + b * HH;
    for (int l = wv; l < LL; l += 4) {
      const float* w = fcw + l * HH;
      float s = 0.f;
#pragma unroll
      for (int k = 0; k < HH / 64; ++k) s += p[k * 64 + lane] * w[k * 64 + lane];
#pragma unroll
      for (int off = 32; off > 0; off >>= 1) s += __shfl_down(s, off);
      if (lane == 0) attn_out[b * LL + l] = s;
    }
  }
}

extern "C" void kernel_launch(void* const* d_in, const int* in_sizes, int n_in,
                              void* d_out, int out_size, void* d_ws, size_t ws_size,
                              hipStream_t stream) {
  // inputs: find_contri, code_output, lengths, contri, fc_w
  const float* code_output = (const float*)d_in[1];
  const int* lengths = (const int*)d_in[2];
  const float* contri = (const float*)d_in[3];
  const float* fcw = (const float*)d_in[4];

  float* out = (float*)d_out;            // attn at [0, B*L)
  float* out2 = out + BB * LL;           // contri_out after

  float* ws = (float*)d_ws;
  float* pool = ws;                      // B*H floats
  int* idx = (int*)(ws + BB * HH);       // B*H ints

  int row_blocks = (BB * HH) / 4;        // 16384
  rowmax_kernel<<<COPYBLK + row_blocks, 256, 0, stream>>>(
      code_output, lengths, contri, pool, idx, out2);

  epilogue_kernel<<<10 + BB, 256, 0, stream>>>(pool, idx, fcw, contri, out, out2);
}

// Round 2
// 645.721 us; speedup vs baseline: 1.0090x; 1.0002x over previous
//
#include <hip/hip_runtime.h>
#include <math.h>

#define BB 128
#define SS 2048
#define HH 512
#define LL 11

typedef float vf4 __attribute__((ext_vector_type(4)));

// Blocks [0, COPYBLK): independent float4 contri copy for b >= 10.
// Blocks [COPYBLK, ...): masked row max + argmax, all loads issued up front.
#define COPYBLK 236  // (BB-10)*SS/4/256 exactly

__global__ __launch_bounds__(256) void rowmax_kernel(
    const float* __restrict__ x,
    const int* __restrict__ lengths,
    const float* __restrict__ contri,
    float* __restrict__ pool,
    int* __restrict__ idx_out,
    float* __restrict__ out2) {
  if (blockIdx.x < COPYBLK) {
    // ---- float4 copy rows for b >= 10 (no dependence on rowmax) ----
    int i4 = blockIdx.x * 256 + threadIdx.x;       // [0, 118*2048/4)
    int t = 10 * SS + i4 * 4;                      // first of 4 consecutive rows
    vf4 c0 = *(const vf4*)(contri + (size_t)t * 2);      // a0 b0 a1 b1
    vf4 c1 = *(const vf4*)(contri + (size_t)t * 2 + 4);  // a2 b2 a3 b3
    vf4 o0, o1, o2;
    o0.x = c0.x; o0.y = c0.y; o0.z = 0.f; o0.w = c0.z;
    o1.x = c0.w; o1.y = 0.f;  o1.z = c1.x; o1.w = c1.y;
    o2.x = 0.f;  o2.y = c1.z; o2.z = c1.w; o2.w = 0.f;
    vf4* dst = (vf4*)(out2 + (size_t)t * 3);
    dst[0] = o0; dst[1] = o1; dst[2] = o2;
    return;
  }

  int wave = (blockIdx.x - COPYBLK) * 4 + (threadIdx.x >> 6);  // row in [0, B*H)
  int lane = threadIdx.x & 63;
  int b = wave >> 9;              // H == 512
  int len = lengths[b];           // len >= 1 guaranteed
  const vf4* row = (const vf4*)(x + (size_t)wave * SS);
  int nj = (len + 255) >> 8;      // chunks holding valid elements, in [1,8]

  // Issue every needed load before any consumer: up to 8 dwordx4 in flight.
  vf4 v0, v1, v2, v3, v4, v5, v6, v7;
  v0 = row[lane];
  if (nj > 1) v1 = row[1 * 64 + lane];
  if (nj > 2) v2 = row[2 * 64 + lane];
  if (nj > 3) v3 = row[3 * 64 + lane];
  if (nj > 4) v4 = row[4 * 64 + lane];
  if (nj > 5) v5 = row[5 * 64 + lane];
  if (nj > 6) v6 = row[6 * 64 + lane];
  if (nj > 7) v7 = row[7 * 64 + lane];

  float best = -INFINITY;
  int bidx = 0;
#define PROC(vv, J)                                              \
  {                                                              \
    int si = ((J) * 64 + lane) * 4;                              \
    float a;                                                     \
    a = (si + 0 < len) ? (vv).x : -INFINITY;                     \
    if (a > best) { best = a; bidx = si + 0; }                   \
    a = (si + 1 < len) ? (vv).y : -INFINITY;                     \
    if (a > best) { best = a; bidx = si + 1; }                   \
    a = (si + 2 < len) ? (vv).z : -INFINITY;                     \
    if (a > best) { best = a; bidx = si + 2; }                   \
    a = (si + 3 < len) ? (vv).w : -INFINITY;                     \
    if (a > best) { best = a; bidx = si + 3; }                   \
  }
  PROC(v0, 0);
  if (nj > 1) PROC(v1, 1);
  if (nj > 2) PROC(v2, 2);
  if (nj > 3) PROC(v3, 3);
  if (nj > 4) PROC(v4, 4);
  if (nj > 5) PROC(v5, 5);
  if (nj > 6) PROC(v6, 6);
  if (nj > 7) PROC(v7, 7);
#undef PROC

  // cross-lane reduce, first-occurrence tie-break (min index on equal value)
#pragma unroll
  for (int off = 32; off > 0; off >>= 1) {
    float ov = __shfl_down(best, off);
    int oi = __shfl_down(bidx, off);
    if (ov > best || (ov == best && oi < bidx)) { best = ov; bidx = oi; }
  }
  if (lane == 0) {
    pool[wave] = best;
    idx_out[wave] = bidx;
  }
}

// ---------------------------------------------------------------------------
// Kernel 2: fused epilogue.
//   blocks [0,10):   per-batch denom + total + LDS scatter + output row
//   blocks [10,138): attn = pool @ fc_w.T for b = blockIdx-10
// ---------------------------------------------------------------------------
__global__ __launch_bounds__(256) void epilogue_kernel(
    const float* __restrict__ pool,
    const int* __restrict__ idx_in,
    const float* __restrict__ fcw,
    const float* __restrict__ contri,
    float* __restrict__ attn_out,
    float* __restrict__ out2) {
  int tid = threadIdx.x;
  int wv = tid >> 6;
  int lane = tid & 63;

  if (blockIdx.x < 10) {
    // ---- special batch: contributions + LDS scatter + row write ----
    int b = blockIdx.x;
    __shared__ float sp[HH];     // pool row
    __shared__ float sden[LL];   // 100/denom
    __shared__ float sch[SS];    // scatter target (ch2 row)

    for (int h = tid; h < HH; h += 256) sp[h] = pool[b * HH + h];
    for (int s = tid; s < SS; s += 256) sch[s] = 0.f;
    __syncthreads();

    // denom[l] = sum_h relu(p*w) + H*1e-4 ; store reciprocal*100
    for (int l = wv; l < LL; l += 4) {
      float s = 0.f;
#pragma unroll
      for (int k = 0; k < HH / 64; ++k) {
        int h = k * 64 + lane;
        s += fmaxf(sp[h] * fcw[l * HH + h], 0.f);
      }
#pragma unroll
      for (int off = 32; off > 0; off >>= 1) s += __shfl_down(s, off);
      if (lane == 0) sden[l] = 100.f / (s + (float)HH * 1e-4f);
    }
    __syncthreads();

    // total[hh] and scatter into LDS
    for (int hh = tid; hh < HH; hh += 256) {
      float p = sp[hh];
      float tot = 0.f;
#pragma unroll
      for (int l = 0; l < LL; ++l)
        tot += (fmaxf(p * fcw[l * HH + hh], 0.f) + 1e-4f) * sden[l];
      atomicAdd(&sch[idx_in[b * HH + hh]], tot);
    }
    __syncthreads();

    // write output rows: (contri0, contri1, ch2)
    for (int s = tid; s < SS; s += 256) {
      int t = b * SS + s;
      out2[t * 3 + 0] = contri[t * 2 + 0];
      out2[t * 3 + 1] = contri[t * 2 + 1];
      out2[t * 3 + 2] = sch[s];
    }
  } else {
    // ---- attn for one batch ----
    int b = blockIdx.x - 10;
    const float* p = pool + b * HH;
    for (int l = wv; l < LL; l += 4) {
      const float* w = fcw + l * HH;
      float s = 0.f;
#pragma unroll
      for (int k = 0; k < HH / 64; ++k) s += p[k * 64 + lane] * w[k * 64 + lane];
#pragma unroll
      for (int off = 32; off > 0; off >>= 1) s += __shfl_down(s, off);
      if (lane == 0) attn_out[b * LL + l] = s;
    }
  }
}

extern "C" void kernel_launch(void* const* d_in, const int* in_sizes, int n_in,
                              void* d_out, int out_size, void* d_ws, size_t ws_size,
                              hipStream_t stream) {
  // inputs: find_contri, code_output, lengths, contri, fc_w
  const float* code_output = (const float*)d_in[1];
  const int* lengths = (const int*)d_in[2];
  const float* contri = (const float*)d_in[3];
  const float* fcw = (const float*)d_in[4];

  float* out = (float*)d_out;            // attn at [0, B*L)
  float* out2 = out + BB * LL;           // contri_out after

  float* ws = (float*)d_ws;
  float* pool = ws;                      // B*H floats
  int* idx = (int*)(ws + BB * HH);       // B*H ints

  int row_blocks = (BB * HH) / 4;        // 16384
  rowmax_kernel<<<COPYBLK + row_blocks, 256, 0, stream>>>(
      code_output, lengths, contri, pool, idx, out2);

  epilogue_kernel<<<10 + BB, 256, 0, stream>>>(pool, idx, fcw, contri, out, out2);
}